// Round 10
// baseline (194.495 us; speedup 1.0000x reference)
//
#include <hip/hip_runtime.h>
#include <cstdint>
#include <cstddef>

#define NA 8400   // anchors per image: 80*80 + 40*40 + 20*20
#define NAP 8448  // padded stride (33*256); ci space is SEGMENTED: blk*256 + local_rank
#define NB 32     // batch
#define NG 20     // ground truths per image
#define NCL 80    // classes
#define NBLK 33   // 256-thread blocks per image

// ---------- fast math ----------
__device__ __forceinline__ float frcp(float x) { return __builtin_amdgcn_rcpf(x); }
__device__ __forceinline__ float bce0(float x) {
  return fmaxf(x, 0.0f) + __logf(1.0f + __expf(-fabsf(x)));
}

__device__ __forceinline__ void anchor_info(int a, const float* p8, const float* p16,
                                            const float* p32, int b, const float*& base,
                                            int& hw, int& HW, int& xg, int& yg, float& fs) {
  if (a < 6400)      { hw = a;        HW = 6400; xg = hw % 80; yg = hw / 80; fs = 8.f;
                       base = p8  + (size_t)b * 85 * 6400; }
  else if (a < 8000) { hw = a - 6400; HW = 1600; xg = hw % 40; yg = hw / 40; fs = 16.f;
                       base = p16 + (size_t)b * 85 * 1600; }
  else               { hw = a - 8000; HW = 400;  xg = hw % 20; yg = hw / 20; fs = 32.f;
                       base = p32 + (size_t)b * 85 * 400; }
}

__device__ __forceinline__ float iou_raw(float gx, float gy, float gw, float gh, float4 p) {
  float gtlx = gx - gw * 0.5f, gtly = gy - gh * 0.5f;
  float gbrx = gx + gw * 0.5f, gbry = gy + gh * 0.5f;
  float ptlx = p.x - p.z * 0.5f, ptly = p.y - p.w * 0.5f;
  float pbrx = p.x + p.z * 0.5f, pbry = p.y + p.w * 0.5f;
  float tlx = fmaxf(gtlx, ptlx), tly = fmaxf(gtly, ptly);
  float brx = fminf(gbrx, pbrx), bry = fminf(gbry, pbry);
  float inter = ((tlx < brx) && (tly < bry)) ? (brx - tlx) * (bry - tly) : 0.0f;
  float ag = gw * gh, ap = p.z * p.w;
  return inter * frcp(ag + ap - inter + 1e-16f);
}

__device__ __forceinline__ float giou_loss(float4 bb, float gx, float gy, float gw, float gh) {
  float btlx = bb.x - bb.z * 0.5f, btly = bb.y - bb.w * 0.5f;
  float bbrx = bb.x + bb.z * 0.5f, bbry = bb.y + bb.w * 0.5f;
  float gtlx = gx - gw * 0.5f, gtly = gy - gh * 0.5f;
  float gbrx = gx + gw * 0.5f, gbry = gy + gh * 0.5f;
  float tlx = fmaxf(btlx, gtlx), tly = fmaxf(btly, gtly);
  float brx = fminf(bbrx, gbrx), bry = fminf(bbry, gbry);
  float area_b = bb.z * bb.w, area_g = gw * gh;
  float inter = ((tlx < brx) && (tly < bry)) ? (brx - tlx) * (bry - tly) : 0.0f;
  float uni = area_b + area_g - inter;
  float iou = inter / (uni + 1e-16f);
  float ctlx = fminf(btlx, gtlx), ctly = fminf(btly, gtly);
  float cbrx = fmaxf(bbrx, gbrx), cbry = fmaxf(bbry, gbry);
  float area_c = fmaxf((cbrx - ctlx) * (cbry - ctly), 1e-16f);
  float giou = iou - (area_c - uni) / area_c;
  giou = fminf(fmaxf(giou, -1.0f), 1.0f);
  return 1.0f - giou;
}

__device__ __forceinline__ void block_argmin(float& v, int& i, volatile float* s_v,
                                             volatile int* s_i, int tid) {
#pragma unroll
  for (int off = 32; off; off >>= 1) {
    float ov = __shfl_down(v, off, 64);
    int   oi = __shfl_down(i, off, 64);
    if (ov < v || (ov == v && oi < i)) { v = ov; i = oi; }
  }
  if ((tid & 63) == 0) { s_v[tid >> 6] = v; s_i[tid >> 6] = i; }
  __syncthreads();
  v = s_v[0]; i = s_i[0];
#pragma unroll
  for (int w = 1; w < 4; ++w) {
    float ov = s_v[w]; int oi = s_i[w];
    if (ov < v || (ov == v && oi < i)) { v = ov; i = oi; }
  }
}

// ---------- kF: geometry + BLOCK-LOCAL (segmented) compaction + class sums +
//              cost/iou tables — fully fused, zero cross-block dependency ----------
__global__ __launch_bounds__(256) void kF(const float* __restrict__ p8,
                                          const float* __restrict__ p16,
                                          const float* __restrict__ p32,
                                          const float* __restrict__ labels,
                                          int* __restrict__ n_seg,
                                          int* __restrict__ a_seg,
                                          float4* __restrict__ bbox_c,
                                          float* __restrict__ sb_c,
                                          float* __restrict__ cost_tbl,
                                          float* __restrict__ iou_tbl,
                                          unsigned int* __restrict__ match_c,
                                          float* __restrict__ blk_obj) {
  __shared__ float s_gt[NG * 4];
  __shared__ int   s_gcls[NG];
  __shared__ int   s_a[256];
  __shared__ unsigned int s_msk[256];
  __shared__ float s_lso[256];
  __shared__ float4 s_bb[256];
  __shared__ unsigned int s_wcnt[4];
  __shared__ float s_part[4];
  __shared__ int   s_cnt;
  __shared__ float s_sl[8][33];
  __shared__ float s_sb[8][33];
  __shared__ float s_slr[32];

  int blk = blockIdx.x, b = blockIdx.y, tid = threadIdx.x, lane = tid & 63, wid = tid >> 6;
  int part = tid >> 5, cl = tid & 31;

  if (tid < NG) {
    s_gt[tid * 4 + 0] = labels[((size_t)b * NG + tid) * 5 + 0];
    s_gt[tid * 4 + 1] = labels[((size_t)b * NG + tid) * 5 + 1];
    s_gt[tid * 4 + 2] = labels[((size_t)b * NG + tid) * 5 + 2];
    s_gt[tid * 4 + 3] = labels[((size_t)b * NG + tid) * 5 + 3];
    s_gcls[tid] = (int)labels[((size_t)b * NG + tid) * 5 + 4];
  }
  __syncthreads();

  size_t bo = (size_t)b * NAP;
  int ci0 = blk * 256;
  int a = ci0 + tid;
  match_c[bo + a] = 0u;                  // full NAP coverage

  // ---- phase 1: geometry + local compaction ----
  bool fg = false;
  unsigned int msk = 0u;
  float bce_obj = 0.0f, obj = 0.0f;
  const float* base = nullptr; int hw = 0, HW = 0, xg = 0, yg = 0; float fs = 8.f;
  if (a < NA) {
    anchor_info(a, p8, p16, p32, b, base, hw, HW, xg, yg, fs);
    obj = base[4 * HW + hw];             // coalesced obj-plane stream
    bce_obj = bce0(obj);
    float xc = ((float)xg + 0.5f) * fs;
    float yc = ((float)yg + 0.5f) * fs;
    float r = 2.5f * fs;
#pragma unroll
    for (int g = 0; g < NG; ++g) {
      float gx = s_gt[g * 4 + 0], gy = s_gt[g * 4 + 1];
      float gw = s_gt[g * 4 + 2], gh = s_gt[g * 4 + 3];
      bool inb = (xc > gx - 0.5f * gw) && (xc < gx + 0.5f * gw) &&
                 (yc > gy - 0.5f * gh) && (yc < gy + 0.5f * gh);
      bool inc = (xc > gx - r) && (xc < gx + r) && (yc > gy - r) && (yc < gy + r);
      fg = fg || inb || inc;
      if (inb && inc) msk |= (1u << g);
    }
  }

  unsigned long long bm = __ballot(fg);
#pragma unroll
  for (int off = 32; off; off >>= 1) bce_obj += __shfl_down(bce_obj, off, 64);
  if (lane == 0) { s_wcnt[wid] = (unsigned int)__popcll(bm); s_part[wid] = bce_obj; }
  __syncthreads();
  if (tid == 0) {
    int cnt = (int)(s_wcnt[0] + s_wcnt[1] + s_wcnt[2] + s_wcnt[3]);
    s_cnt = cnt;
    n_seg[b * NBLK + blk] = cnt;
    blk_obj[b * NBLK + blk] = s_part[0] + s_part[1] + s_part[2] + s_part[3];
  }
  if (fg) {
    unsigned int li = 0;
    for (int w = 0; w < wid; ++w) li += s_wcnt[w];
    li += (unsigned int)__popcll(bm & ((1ull << lane) - 1ull));
    s_a[li] = a;
    s_msk[li] = msk;
    float v0 = base[hw];
    float v1 = base[HW + hw];
    float v2 = base[2 * HW + hw];
    float v3 = base[3 * HW + hw];
    float4 pb = make_float4((v0 + (float)xg) * fs, (v1 + (float)yg) * fs,
                            __expf(v2) * fs, __expf(v3) * fs);
    s_bb[li] = pb;
    // log(sigmoid(obj)) = min(obj,0) - log(1+exp(-|obj|))
    float uo = __logf(1.0f + __expf(-fabsf(obj)));
    s_lso[li] = fminf(obj, 0.0f) - uo;
    a_seg[bo + ci0 + li] = a;
    bbox_c[bo + ci0 + li] = pb;
  }
  __syncthreads();

  // ---- phase 2: class sums (8 parts x 32 anchors) + cost/iou per tile ----
  int cnt = s_cnt;
  for (int t0 = 0; t0 < cnt; t0 += 32) {
    int idx = t0 + cl;
    bool act = idx < cnt;
    const float* cbase = nullptr; int chw = 0, cHW = 0, cxg, cyg; float cfs;
    float lso = 0.0f, sl = 0.0f, sb = 0.0f;
    if (act) {
      int aa = s_a[idx];
      lso = s_lso[idx];
      anchor_info(aa, p8, p16, p32, b, cbase, chw, cHW, cxg, cyg, cfs);
      const float* cb = cbase + (size_t)(5 + part * 10) * cHW + chw;
      float xs[10];
#pragma unroll
      for (int j = 0; j < 10; ++j) xs[j] = cb[(size_t)j * cHW];
#pragma unroll
      for (int j = 0; j < 10; ++j) {
        float x = xs[j];
        float u = __logf(1.0f + __expf(-fabsf(x)));
        sb += fmaxf(x, 0.0f) + u;                 // bce(x,0)
        float lsx = fminf(x, 0.0f) - u;           // log(sigmoid(x))
        float lpr = 0.5f * (lsx + lso);           // log p
        float p   = __expf(lpr);
        sl += fmaxf(__logf(1.0f - p), -100.0f);
      }
    }
    s_sl[part][cl] = sl;
    s_sb[part][cl] = sb;
    __syncthreads();
    if (tid < 32) {
      float tsl = 0.0f, tsb = 0.0f;
#pragma unroll
      for (int q = 0; q < 8; ++q) { tsl += s_sl[q][tid]; tsb += s_sb[q][tid]; }
      s_slr[tid] = tsl;
      if (t0 + tid < cnt) sb_c[bo + ci0 + t0 + tid] = tsb;
    }
    __syncthreads();
    if (act) {
      float slr = s_slr[cl];
      unsigned int am = s_msk[idx];
      float4 pb = s_bb[idx];
#pragma unroll
      for (int gg = 0; gg < 3; ++gg) {
        int g = part + (gg << 3);
        if (g < NG) {
          int cg = s_gcls[g];
          float x = cbase[(size_t)(5 + cg) * cHW + chw];
          float u = __logf(1.0f + __expf(-fabsf(x)));
          float lsx = fminf(x, 0.0f) - u;
          float lpr = 0.5f * (lsx + lso);
          float p   = __expf(lpr);
          float l1p = fmaxf(__logf(1.0f - p), -100.0f);
          float wv  = fmaxf(lpr, -100.0f) - l1p;  // lp - l1p
          float iou = iou_raw(s_gt[g * 4 + 0], s_gt[g * 4 + 1],
                              s_gt[g * 4 + 2], s_gt[g * 4 + 3], pb);
          float cst = -(wv + slr) - 3.0f * __logf(iou + 1e-8f);
          if (!((am >> g) & 1u)) cst += 100000.0f;
          size_t row = ((size_t)b * NG + g) * NAP;
          cost_tbl[row + ci0 + idx] = cst;
          iou_tbl[row + ci0 + idx]  = iou;
        }
      }
    }
    __syncthreads();   // protect LDS reuse next tile
  }
}

// ---------- kBCD: per-(b,g) top-k + per-image finalize ticket + final scalar ----------
__global__ __launch_bounds__(256) void kBCD(const float* __restrict__ p8,
                                            const float* __restrict__ p16,
                                            const float* __restrict__ p32,
                                            const float* __restrict__ labels,
                                            const float* __restrict__ cost_tbl,
                                            const float* __restrict__ iou_tbl,
                                            const int* __restrict__ n_seg,
                                            unsigned int* __restrict__ match_c,
                                            const int* __restrict__ a_seg,
                                            const float4* __restrict__ bbox_c,
                                            const float* __restrict__ sb_c,
                                            const float* __restrict__ blk_obj,
                                            float* __restrict__ accum,
                                            int* __restrict__ done_g,
                                            int* __restrict__ done_img,
                                            float* __restrict__ out) {
  __shared__ float s_cost[NAP];   // 33 KB
  __shared__ int   s_nseg[NBLK];
  __shared__ float s_wt[4 * 10];
  __shared__ float s_v[4];
  __shared__ int   s_i[4];
  __shared__ int   s_k;
  __shared__ int   s_flag;
  __shared__ float s_gt[NG * 5];
  __shared__ float s_red[16];

  int g = blockIdx.x, b = blockIdx.y, tid = threadIdx.x;
  int lane = tid & 63, wid = tid >> 6;
  size_t bo = (size_t)b * NAP;
  const float* __restrict__ cg = cost_tbl + ((size_t)b * NG + g) * NAP;
  const float* __restrict__ ig = iou_tbl  + ((size_t)b * NG + g) * NAP;

  if (tid < NBLK) s_nseg[tid] = n_seg[b * NBLK + tid];
  __syncthreads();

  float t10[10];
#pragma unroll
  for (int j = 0; j < 10; ++j) t10[j] = 0.0f;

  // fill: ci = it*256 + tid -> segment blk == it, local == tid
  for (int it = 0; it < NBLK; ++it) {
    int ci = it * 256 + tid;
    bool valid = tid < s_nseg[it];
    float iou = valid ? ig[ci] : 0.0f;     // holes ~ iou 0 (matches ref's zero-mask)
    float cst = valid ? cg[ci] : 1e9f;     // holes never selected
    if (iou > t10[9]) {
      t10[9] = iou;
#pragma unroll
      for (int q = 9; q > 0; --q) {
        if (t10[q] > t10[q - 1]) { float t = t10[q]; t10[q] = t10[q - 1]; t10[q - 1] = t; }
        else break;
      }
    }
    s_cost[ci] = cst;
  }

  // per-wave top-10 extraction (regs+shuffles, no syncs), then 4-list merge
  for (int r = 0; r < 10; ++r) {
    float v = t10[0];
    float bv = v;
#pragma unroll
    for (int off = 32; off; off >>= 1) bv = fmaxf(bv, __shfl_down(bv, off, 64));
    bv = __shfl(bv, 0, 64);
    unsigned long long won = __ballot(v == bv);
    if (lane == __ffsll(won) - 1) {
#pragma unroll
      for (int q = 0; q < 9; ++q) t10[q] = t10[q + 1];
      t10[9] = -1.0f;
    }
    if (lane == 0) s_wt[wid * 10 + r] = bv;
  }
  __syncthreads();

  if (tid == 0) {
    int p0 = 0, p1 = 0, p2 = 0, p3 = 0;
    float s = 0.0f;
    for (int r = 0; r < 10; ++r) {
      float v0 = (p0 < 10) ? s_wt[p0]      : -2.0f;
      float v1 = (p1 < 10) ? s_wt[10 + p1] : -2.0f;
      float v2 = (p2 < 10) ? s_wt[20 + p2] : -2.0f;
      float v3 = (p3 < 10) ? s_wt[30 + p3] : -2.0f;
      float m = fmaxf(fmaxf(v0, v1), fmaxf(v2, v3));
      s += m;
      if (m == v0) ++p0; else if (m == v1) ++p1; else if (m == v2) ++p2; else ++p3;
    }
    int k = (int)s;                 // truncation matches astype(int32)
    if (k < 1) k = 1;
    s_k = k;
  }
  __syncthreads();
  int k = s_k;

  // extract k smallest; (cost, ci) lexicographic; ci order == anchor order
  for (int it = 0; it < k; ++it) {
    float bv = 3.4e38f; int bi = NAP;
    for (int ci = tid; ci < NAP; ci += 256) {
      float v = s_cost[ci];
      if (v < bv || (v == bv && ci < bi)) { bv = v; bi = ci; }
    }
    block_argmin(bv, bi, s_v, s_i, tid);
    if (bv >= 1e8f) break;          // only holes / exhausted candidates left
    if (tid == 0) {
      atomicOr(&match_c[bo + bi], 1u << g);
      s_cost[bi] = 3.4e38f;
    }
    __syncthreads();
  }

  // ---- per-image ticket: 20th row-block of image b runs the finalize scan ----
  __syncthreads();
  if (tid == 0) {
    __threadfence();
    s_flag = (atomicAdd(&done_g[b], 1) == NG - 1) ? 1 : 0;
  }
  __syncthreads();
  if (!s_flag) return;

  if (tid < NG * 5) s_gt[tid] = labels[(size_t)b * NG * 5 + tid];
  __syncthreads();

  float li = 0.0f, oe = 0.0f, lc = 0.0f, nf = 0.0f;
  for (int ci = tid; ci < NAP; ci += 256) {
    unsigned int m = atomicOr(&match_c[bo + ci], 0u);   // coherence-point read
    if (m == 0u) continue;
    int mg;
    if (m & (m - 1)) {
      float bestc = 3.4e38f; mg = 0;
#pragma unroll 4
      for (int gq = 0; gq < NG; ++gq) {
        float cst = cost_tbl[((size_t)b * NG + gq) * NAP + ci];
        if (cst < bestc) { bestc = cst; mg = gq; }
      }
    } else {
      mg = __ffs(m) - 1;
    }
    int a = a_seg[bo + ci];
    const float* base; int hw, HW, xg, yg; float fs;
    anchor_info(a, p8, p16, p32, b, base, hw, HW, xg, yg, fs);
    float4 pb = bbox_c[bo + ci];
    float gx = s_gt[mg * 5], gy = s_gt[mg * 5 + 1];
    float gw = s_gt[mg * 5 + 2], gh = s_gt[mg * 5 + 3];
    int cgq = (int)s_gt[mg * 5 + 4];
    float piou = iou_tbl[((size_t)b * NG + mg) * NAP + ci];
    li += giou_loss(pb, gx, gy, gw, gh);
    float xcls = base[(size_t)(5 + cgq) * HW + hw];
    lc += sb_c[bo + ci] - xcls * piou;   // bce(x,t) = bce(x,0) - x*t
    oe += base[4 * HW + hw];             // obj logit: bce(x,1) = bce(x,0) - x
    nf += 1.0f;
  }

  float vals[4] = {li, oe, lc, nf};
#pragma unroll
  for (int q = 0; q < 4; ++q) {
#pragma unroll
    for (int off = 32; off; off >>= 1) vals[q] += __shfl_down(vals[q], off, 64);
  }
  if ((tid & 63) == 0) {
    int w = tid >> 6;
    s_red[w * 4 + 0] = vals[0];
    s_red[w * 4 + 1] = vals[1];
    s_red[w * 4 + 2] = vals[2];
    s_red[w * 4 + 3] = vals[3];
  }
  __syncthreads();
  if (tid < 4) {
    const int slot[4] = {0, 2, 3, 4};
    float s = s_red[tid] + s_red[4 + tid] + s_red[8 + tid] + s_red[12 + tid];
    atomicAdd(&accum[slot[tid]], s);
  }

  // ---- final ticket: last image's finalize block emits the scalar ----
  if (tid == 0) {
    __threadfence();
    s_flag = (atomicAdd(done_img, 1) == NB - 1) ? 1 : 0;
  }
  __syncthreads();
  if (!s_flag) return;

  float s = 0.0f;
  for (int i = tid; i < NB * NBLK; i += 256) s += blk_obj[i];  // obj-BCE base
#pragma unroll
  for (int off = 32; off; off >>= 1) s += __shfl_down(s, off, 64);
  if ((tid & 63) == 0) s_red[tid >> 6] = s;
  __syncthreads();
  if (tid == 0) {
    float obj_base = s_red[0] + s_red[1] + s_red[2] + s_red[3];
    float loss_iou = atomicAdd(&accum[0], 0.0f);   // coherent read-backs
    float oex      = atomicAdd(&accum[2], 0.0f);
    float loss_cls = atomicAdd(&accum[3], 0.0f);
    float num_fg   = atomicAdd(&accum[4], 0.0f);
    float loss_obj = obj_base - oex;
    out[0] = (5.0f * loss_iou + loss_obj + loss_cls) / fmaxf(num_fg, 1.0f);
  }
}

// ---------- launch ----------
extern "C" void kernel_launch(void* const* d_in, const int* in_sizes, int n_in,
                              void* d_out, int out_size, void* d_ws, size_t ws_size,
                              hipStream_t stream) {
  const float* p8     = (const float*)d_in[0];
  const float* p16    = (const float*)d_in[1];
  const float* p32    = (const float*)d_in[2];
  const float* labels = (const float*)d_in[3];
  float* out = (float*)d_out;

  const size_t BAP = (size_t)NB * NAP;     // 270336
  char* w = (char*)d_ws;
  float4*       bbox_c   = (float4*)w;                             // 4.3 MB, 16B-aligned
  float*        cost_tbl = (float*)(w + BAP * 16);                 // NB*NG*NAP*4 = 21.6 MB
  float*        iou_tbl  = cost_tbl + (size_t)NB * NG * NAP;       // 21.6 MB
  char*         w2       = (char*)(iou_tbl + (size_t)NB * NG * NAP);
  int*          a_seg    = (int*)(w2);
  unsigned int* match_c  = (unsigned int*)(w2 + BAP * 4);
  float*        sb_c     = (float*)(w2 + BAP * 8);
  char*         w3       = w2 + BAP * 12;
  // zeroed region (512 B): accum(8f)@0, done_g(32i)@128, done_img@256
  float*        accum    = (float*)(w3);
  int*          done_g   = (int*)(w3 + 128);
  int*          done_img = (int*)(w3 + 256);
  int*          n_seg    = (int*)(w3 + 512);                       // NB*NBLK ints (kF writes all)
  float*        blk_obj  = (float*)(w3 + 512 + NB * NBLK * 4);     // NB*NBLK floats

  hipMemsetAsync(w3, 0, 512, stream);

  kF<<<dim3(NBLK, NB), dim3(256), 0, stream>>>(p8, p16, p32, labels, n_seg, a_seg,
                                               bbox_c, sb_c, cost_tbl, iou_tbl,
                                               match_c, blk_obj);
  kBCD<<<dim3(NG, NB), dim3(256), 0, stream>>>(p8, p16, p32, labels, cost_tbl, iou_tbl,
                                               n_seg, match_c, a_seg, bbox_c, sb_c,
                                               blk_obj, accum, done_g, done_img, out);
}